// Round 1
// baseline (943.925 us; speedup 1.0000x reference)
//
#include <hip/hip_runtime.h>

#define N_IN   262144
#define N_OUT  262144
#define KOFF   27
#define MPAIR  131072
#define C      64
#define EPS    1e-5f
#define NEG_SLOPE 0.01f

// ---------------------------------------------------------------------------
// Conv: one wave per pair (64 pairs per wave, looped). lane = output channel.
// W[k][:,lane] held in 64 VGPRs. feats row staged via LDS ring, read back as
// uniform-address float4 broadcasts. Scatter via HW fp32 atomics.
// ---------------------------------------------------------------------------
__global__ __launch_bounds__(256) void conv_kernel(
    const float* __restrict__ feats,
    const float* __restrict__ W,
    const int*   __restrict__ in_map,
    const int*   __restrict__ out_map,
    float*       __restrict__ out)
{
    const int k    = blockIdx.y;
    const int lane = threadIdx.x & 63;
    const int wave = threadIdx.x >> 6;

    __shared__ float4 fr4[4][2][16];   // [wave][ring buf][16 x float4 = 64 floats]

    // Register-resident weight column: wreg[i] = W[k][i][lane]
    float wreg[C];
    const float* Wk = W + (size_t)k * C * C;
    #pragma unroll
    for (int i = 0; i < C; ++i) wreg[i] = Wk[i * C + lane];

    // Each wave owns 64 consecutive pairs; lane l pre-loads pair l's indices.
    const int pair_base = (blockIdx.x * 4 + wave) * 64;
    const int my_pair   = pair_base + lane;
    const int my_im = in_map[(size_t)k * MPAIR + my_pair];
    const int my_om = out_map[(size_t)k * MPAIR + my_pair];

    // Prefetch first row
    int im0 = __builtin_amdgcn_readlane(my_im, 0);
    float fcur = feats[(size_t)im0 * C + lane];

    for (int p = 0; p < 64; ++p) {
        const int om  = __builtin_amdgcn_readlane(my_om, p);
        const int buf = p & 1;

        ((float*)&fr4[wave][buf][0])[lane] = fcur;

        if (p < 63) {
            int imn = __builtin_amdgcn_readlane(my_im, p + 1);
            fcur = feats[(size_t)imn * C + lane];   // overlaps compute below
        }

        float acc = 0.f;
        #pragma unroll
        for (int j = 0; j < 16; ++j) {
            float4 f = fr4[wave][buf][j];           // uniform addr -> broadcast
            acc = fmaf(f.x, wreg[4*j+0], acc);
            acc = fmaf(f.y, wreg[4*j+1], acc);
            acc = fmaf(f.z, wreg[4*j+2], acc);
            acc = fmaf(f.w, wreg[4*j+3], acc);
        }

        unsafeAtomicAdd(&out[(size_t)om * C + lane], acc);  // HW global_atomic_add_f32
    }
}

// ---------------------------------------------------------------------------
// Per-channel sum / sumsq over out[N_OUT][64], float4-vectorized.
// stats[0..63] = sum, stats[64..127] = sumsq.
// ---------------------------------------------------------------------------
__global__ __launch_bounds__(256) void stats_kernel(
    const float* __restrict__ out, float* __restrict__ stats)
{
    __shared__ float4 s_sum[256], s_sq[256];
    const int col4 = threadIdx.x & 15;   // channel group: channels 4*col4 .. +3
    const int rowg = threadIdx.x >> 4;   // 16 rows per block-iteration

    float4 s = make_float4(0.f, 0.f, 0.f, 0.f);
    float4 q = make_float4(0.f, 0.f, 0.f, 0.f);
    for (int row = blockIdx.x * 16 + rowg; row < N_OUT; row += gridDim.x * 16) {
        float4 v = *(const float4*)(out + (size_t)row * C + col4 * 4);
        s.x += v.x; s.y += v.y; s.z += v.z; s.w += v.w;
        q.x = fmaf(v.x, v.x, q.x); q.y = fmaf(v.y, v.y, q.y);
        q.z = fmaf(v.z, v.z, q.z); q.w = fmaf(v.w, v.w, q.w);
    }
    s_sum[threadIdx.x] = s; s_sq[threadIdx.x] = q;
    __syncthreads();

    if (threadIdx.x < 16) {
        float4 ts = make_float4(0.f, 0.f, 0.f, 0.f);
        float4 tq = make_float4(0.f, 0.f, 0.f, 0.f);
        for (int j = 0; j < 16; ++j) {
            float4 a = s_sum[j * 16 + threadIdx.x];
            float4 b = s_sq [j * 16 + threadIdx.x];
            ts.x += a.x; ts.y += a.y; ts.z += a.z; ts.w += a.w;
            tq.x += b.x; tq.y += b.y; tq.z += b.z; tq.w += b.w;
        }
        const int c0 = threadIdx.x * 4;
        unsafeAtomicAdd(&stats[c0 + 0], ts.x);
        unsafeAtomicAdd(&stats[c0 + 1], ts.y);
        unsafeAtomicAdd(&stats[c0 + 2], ts.z);
        unsafeAtomicAdd(&stats[c0 + 3], ts.w);
        unsafeAtomicAdd(&stats[64 + c0 + 0], tq.x);
        unsafeAtomicAdd(&stats[64 + c0 + 1], tq.y);
        unsafeAtomicAdd(&stats[64 + c0 + 2], tq.z);
        unsafeAtomicAdd(&stats[64 + c0 + 3], tq.w);
    }
}

// ---------------------------------------------------------------------------
// In-place BN (affine) + LeakyReLU, float4-vectorized.
// ---------------------------------------------------------------------------
__global__ __launch_bounds__(256) void bn_kernel(
    float* __restrict__ out,
    const float* __restrict__ stats,
    const float* __restrict__ gamma,
    const float* __restrict__ beta)
{
    __shared__ __align__(16) float s_scale[C];
    __shared__ __align__(16) float s_shift[C];
    if (threadIdx.x < C) {
        const float inv_n = 1.0f / (float)N_OUT;
        float mean = stats[threadIdx.x] * inv_n;
        float var  = stats[C + threadIdx.x] * inv_n - mean * mean;
        float sc   = gamma[threadIdx.x] * rsqrtf(var + EPS);
        s_scale[threadIdx.x] = sc;
        s_shift[threadIdx.x] = beta[threadIdx.x] - mean * sc;
    }
    __syncthreads();

    const int col4 = threadIdx.x & 15;
    const int rowg = threadIdx.x >> 4;
    const float4 sc4 = *(const float4*)&s_scale[col4 * 4];
    const float4 sh4 = *(const float4*)&s_shift[col4 * 4];

    for (int row = blockIdx.x * 16 + rowg; row < N_OUT; row += gridDim.x * 16) {
        float4* p = (float4*)(out + (size_t)row * C + col4 * 4);
        float4 v = *p;
        v.x = fmaf(v.x, sc4.x, sh4.x);
        v.y = fmaf(v.y, sc4.y, sh4.y);
        v.z = fmaf(v.z, sc4.z, sh4.z);
        v.w = fmaf(v.w, sc4.w, sh4.w);
        v.x = v.x >= 0.f ? v.x : NEG_SLOPE * v.x;
        v.y = v.y >= 0.f ? v.y : NEG_SLOPE * v.y;
        v.z = v.z >= 0.f ? v.z : NEG_SLOPE * v.z;
        v.w = v.w >= 0.f ? v.w : NEG_SLOPE * v.w;
        *p = v;
    }
}

extern "C" void kernel_launch(void* const* d_in, const int* in_sizes, int n_in,
                              void* d_out, int out_size, void* d_ws, size_t ws_size,
                              hipStream_t stream) {
    const float* feats  = (const float*)d_in[0];
    const float* W      = (const float*)d_in[1];
    const float* gamma  = (const float*)d_in[2];
    const float* beta   = (const float*)d_in[3];
    const int*  in_map  = (const int*)d_in[4];
    const int*  out_map = (const int*)d_in[5];
    // d_in[6] = num_out (known constant N_OUT)

    float* out   = (float*)d_out;
    float* stats = (float*)d_ws;   // 128 floats

    // Zero accumulation buffer + stats (d_out/d_ws are re-poisoned each call)
    hipMemsetAsync(out, 0, (size_t)N_OUT * C * sizeof(float), stream);
    hipMemsetAsync(stats, 0, 2 * C * sizeof(float), stream);

    dim3 cgrid(MPAIR / 256, KOFF);   // 256 pairs per block (4 waves x 64)
    conv_kernel<<<cgrid, 256, 0, stream>>>(feats, W, in_map, out_map, out);
    stats_kernel<<<256, 256, 0, stream>>>(out, stats);
    bn_kernel<<<512, 256, 0, stream>>>(out, stats, gamma, beta);
}